// Round 3
// baseline (554.659 us; speedup 1.0000x reference)
//
#include <hip/hip_runtime.h>

#define DI __device__ __forceinline__

typedef __attribute__((ext_vector_type(8))) short bf16x8;  // 8 bf16 bit-patterns
typedef __attribute__((ext_vector_type(4))) float f32x4;

DI short f2bs(float x){ unsigned u = __float_as_uint(x);
  return (short)((u + 0x7FFF + ((u >> 16) & 1)) >> 16); }          // RNE f32->bf16
DI float bs2f(short s){ return __uint_as_float(((unsigned)(unsigned short)s) << 16); }
DI f32x4 MFMA(bf16x8 a, bf16x8 b, f32x4 c){
  return __builtin_amdgcn_mfma_f32_16x16x32_bf16(a, b, c, 0, 0, 0);
}

// Problem constants
constexpr int NP   = 8192;
constexpr int NTOT = 16384;     // B*NP (reference flattens batch)
constexpr int M    = 4096;      // B*M_ROIS
constexpr int C    = 128;
constexpr int O    = 256;
constexpr int NS   = 32;
constexpr int H    = 4;
constexpr int KP   = 160;       // padded K: 0..127 feats, 128..130 gx, rest 0
constexpr int GFS  = 168;       // gf LDS row stride (shorts): 336B, 16B-aligned rows
constexpr int VS   = 264;       // v LDS row stride (shorts): 528B
constexpr float BNS = 0.99999500003749969f;  // 1/sqrt(1+1e-5)

// ---------------- K0a: features (B,C,NP) f32 -> fT hi/lo bf16 [B*NP][C] ----------------
__global__ __launch_bounds__(256) void k_transpose(const float* __restrict__ feat,
                                                   short* __restrict__ fTh,
                                                   short* __restrict__ fTl){
  __shared__ float tile[128][65];
  int blk = blockIdx.x;
  int b  = blk >> 7;
  int n0 = (blk & 127) << 6;
  int t = threadIdx.x;
  int nn = t & 63, c4 = t >> 6;
  const float* src = feat + (size_t)b * C * NP;
  for(int i = 0; i < 32; i++){
    int c = c4 * 32 + i;
    tile[c][nn] = src[(size_t)c * NP + n0 + nn];
  }
  __syncthreads();
  int c2 = t & 127, nb = t >> 7;
  for(int j = 0; j < 32; j++){
    int n = nb + j * 2;
    float v = tile[c2][n];
    short hi = f2bs(v);
    short lo = f2bs(v - bs2f(hi));
    size_t o = ((size_t)(b * NP + n0 + n)) * C + c2;
    fTh[o] = hi; fTl[o] = lo;
  }
}

// ---------------- K0b: pack/split weights ----------------
__global__ __launch_bounds__(256) void k_pack(
    const float* __restrict__ kw, const float* __restrict__ v1w,
    const float* __restrict__ v2w,
    const float* __restrict__ vcw, const float* __restrict__ qcw,
    const float* __restrict__ kcw, const float* __restrict__ qkcw,
    const float* __restrict__ cw1, const float* __restrict__ rw1,
    short* __restrict__ keyPh, short* __restrict__ keyPl,
    short* __restrict__ v1Ph,  short* __restrict__ v1Pl,
    short* __restrict__ v2h,   short* __restrict__ v2l,
    short* __restrict__ gw,            // 4 x O x O bf16 (vc,qc,kc,qkc)
    short* __restrict__ cw1b, short* __restrict__ rw1b)
{
  int i = blockIdx.x * 256 + threadIdx.x;
  if(i < O * KP){
    int o = i / KP, k = i % KP;
    float a = 0.0f, b = 0.0f;
    if(k < 128){ a = kw[o*131 + 3 + k]; b = v1w[o*131 + 3 + k]; }
    else if(k < 131){ a = kw[o*131 + (k - 128)]; b = v1w[o*131 + (k - 128)]; }
    short ah = f2bs(a); keyPh[i] = ah; keyPl[i] = f2bs(a - bs2f(ah));
    short bh = f2bs(b); v1Ph[i]  = bh; v1Pl[i]  = f2bs(b - bs2f(bh));
  }
  if(i < O * O){
    float v = v2w[i];
    short hi = f2bs(v); v2h[i] = hi; v2l[i] = f2bs(v - bs2f(hi));
    gw[0*O*O + i] = f2bs(vcw[i]);
    gw[1*O*O + i] = f2bs(qcw[i]);
    gw[2*O*O + i] = f2bs(kcw[i]);
    gw[3*O*O + i] = f2bs(qkcw[i]);
  }
  if(i < (O/2) * O){
    cw1b[i] = f2bs(cw1[i]);
    rw1b[i] = f2bs(rw1[i]);
  }
}

// ---------------- K1: ball query, 1 wave per query (exact f32) ----------------
__global__ __launch_bounds__(64) void k_ballq(const float* __restrict__ xyz,
                                              const float* __restrict__ nxyz,
                                              int* __restrict__ idxo,
                                              float* __restrict__ gxo){
#pragma clang fp contract(off)
  int m = blockIdx.x;
  int lane = threadIdx.x;
  float qx = nxyz[m*3+0], qy = nxyz[m*3+1], qz = nxyz[m*3+2];
  __shared__ int sel[NS];
  int cnt = 0;
  for(int base = 0; base < NTOT; base += 64){
    int p = base + lane;
    float dx = qx - xyz[p*3+0], dy = qy - xyz[p*3+1], dz = qz - xyz[p*3+2];
    float d2 = dx*dx + dy*dy;     // numpy order: (x^2+y^2)+z^2, no contraction
    d2 = d2 + dz*dz;
    bool pred = d2 < 2.56f;       // NEP-50: f32 strict compare
    unsigned long long bal = __ballot(pred);
    if(pred){
      int pos = cnt + __popcll(bal & ((1ull << lane) - 1ull));
      if(pos < NS) sel[pos] = p;
    }
    cnt += __popcll(bal);
    if(cnt >= NS) break;          // wave-uniform
  }
  __syncthreads();
  if(lane < NS){
    int s = 0;
    if(cnt > 0) s = (lane < cnt) ? sel[lane] : sel[0];  // pad with first; empty -> 0
    idxo[m*NS + lane] = s;
    gxo[(m*NS+lane)*3+0] = xyz[s*3+0] - qx;
    gxo[(m*NS+lane)*3+1] = xyz[s*3+1] - qy;
    gxo[(m*NS+lane)*3+2] = xyz[s*3+2] - qz;
  }
}

// ---------------- K2: fused convs + means, split-bf16 MFMA ----------------
__global__ __launch_bounds__(256) void k_conv(
    const short* __restrict__ fTh, const short* __restrict__ fTl,
    const short* __restrict__ keyPh, const short* __restrict__ keyPl,
    const short* __restrict__ v1Ph, const short* __restrict__ v1Pl,
    const short* __restrict__ v2h, const short* __restrict__ v2l,
    const float* __restrict__ posw,
    const float* __restrict__ g1, const float* __restrict__ b1,
    const float* __restrict__ g2, const float* __restrict__ b2,
    const int* __restrict__ idxw, const float* __restrict__ gxw,
    short* __restrict__ keyo, short* __restrict__ valo,
    float* __restrict__ mPos, float* __restrict__ mKey, float* __restrict__ mPK,
    int q0)
{
  int lq = blockIdx.x, q = q0 + lq, t = threadIdx.x;
  int w = t >> 6, l = t & 63;
  int col = l & 15, kq = l >> 4;
  int ro = w * 64;
  __shared__ __align__(16) short gfh[NS * GFS], gfl[NS * GFS];
  __shared__ __align__(16) short vshh[NS * VS], vshl[NS * VS];
  __shared__ float gxs[NS * 4];
  __shared__ float pwsh[O * 3];
  __shared__ int  sel[NS];
  if(t < NS){
    sel[t] = idxw[q*NS + t];
    gxs[t*4+0] = gxw[(q*NS+t)*3+0];
    gxs[t*4+1] = gxw[(q*NS+t)*3+1];
    gxs[t*4+2] = gxw[(q*NS+t)*3+2];
    gxs[t*4+3] = 0.0f;
  }
  for(int i = t; i < O*3; i += 256) pwsh[i] = posw[i];
  __syncthreads();
  // gather features (hi/lo), wave w -> neighbors 8w..8w+7, lane covers 2 channels
  for(int i = 0; i < 8; i++){
    int n = w*8 + i;
    int p = sel[n];
    *(unsigned*)&gfh[n*GFS + l*2] = *(const unsigned*)(fTh + (size_t)p * C + l*2);
    *(unsigned*)&gfl[n*GFS + l*2] = *(const unsigned*)(fTl + (size_t)p * C + l*2);
  }
  // gx channels 128..130 + zero pad to 159
  {
    int n = t & 31, kk = (t >> 5) * 4;
    for(int j = 0; j < 4; j++){
      int k = kk + j;
      float v = (k < 3) ? gxs[n*4 + k] : 0.0f;
      short hi = f2bs(v);
      gfh[n*GFS + 128 + k] = hi;
      gfl[n*GFS + 128 + k] = f2bs(v - bs2f(hi));
    }
  }
  __syncthreads();

  f32x4 acc[4][2];
  const f32x4 vzero = {0.0f, 0.0f, 0.0f, 0.0f};

  // ---- key = relu(W_key @ gf), split-bf16 ----
  for(int mt=0;mt<4;mt++) for(int nt=0;nt<2;nt++) acc[mt][nt] = vzero;
  for(int ks = 0; ks < 5; ks++){
    bf16x8 bh0 = *(const bf16x8*)&gfh[col*GFS + ks*32 + kq*8];
    bf16x8 bh1 = *(const bf16x8*)&gfh[(16+col)*GFS + ks*32 + kq*8];
    bf16x8 bl0 = *(const bf16x8*)&gfl[col*GFS + ks*32 + kq*8];
    bf16x8 bl1 = *(const bf16x8*)&gfl[(16+col)*GFS + ks*32 + kq*8];
    for(int mt = 0; mt < 4; mt++){
      size_t wo = (size_t)(ro + mt*16 + col)*KP + ks*32 + kq*8;
      bf16x8 ah = *(const bf16x8*)(keyPh + wo);
      bf16x8 al = *(const bf16x8*)(keyPl + wo);
      acc[mt][0] = MFMA(al, bh0, MFMA(ah, bl0, MFMA(ah, bh0, acc[mt][0])));
      acc[mt][1] = MFMA(al, bh1, MFMA(ah, bl1, MFMA(ah, bh1, acc[mt][1])));
    }
  }
  float keyR[4][2][4];
  for(int mt=0;mt<4;mt++) for(int nt=0;nt<2;nt++) for(int r=0;r<4;r++){
    float v = fmaxf(acc[mt][nt][r], 0.0f);
    keyR[mt][nt][r] = v;
    int o = ro + mt*16 + kq*4 + r;
    int n = nt*16 + col;
    keyo[((size_t)lq*NS + n)*O + o] = f2bs(v);
  }

  // ---- pos = relu(pos_w @ gx), f32 VALU ----
  float posR[4][2][4];
  for(int mt=0;mt<4;mt++) for(int r=0;r<4;r++){
    int o = ro + mt*16 + kq*4 + r;
    float w0 = pwsh[o*3+0], w1 = pwsh[o*3+1], w2 = pwsh[o*3+2];
    for(int nt=0;nt<2;nt++){
      int n = nt*16 + col;
      float pv = w0*gxs[n*4+0] + w1*gxs[n*4+1] + w2*gxs[n*4+2];
      posR[mt][nt][r] = fmaxf(pv, 0.0f);
    }
  }

  // ---- v = relu(bn1(W_v1 @ gf)), split-bf16 -> LDS hi/lo ----
  for(int mt=0;mt<4;mt++) for(int nt=0;nt<2;nt++) acc[mt][nt] = vzero;
  for(int ks = 0; ks < 5; ks++){
    bf16x8 bh0 = *(const bf16x8*)&gfh[col*GFS + ks*32 + kq*8];
    bf16x8 bh1 = *(const bf16x8*)&gfh[(16+col)*GFS + ks*32 + kq*8];
    bf16x8 bl0 = *(const bf16x8*)&gfl[col*GFS + ks*32 + kq*8];
    bf16x8 bl1 = *(const bf16x8*)&gfl[(16+col)*GFS + ks*32 + kq*8];
    for(int mt = 0; mt < 4; mt++){
      size_t wo = (size_t)(ro + mt*16 + col)*KP + ks*32 + kq*8;
      bf16x8 ah = *(const bf16x8*)(v1Ph + wo);
      bf16x8 al = *(const bf16x8*)(v1Pl + wo);
      acc[mt][0] = MFMA(al, bh0, MFMA(ah, bl0, MFMA(ah, bh0, acc[mt][0])));
      acc[mt][1] = MFMA(al, bh1, MFMA(ah, bl1, MFMA(ah, bh1, acc[mt][1])));
    }
  }
  for(int mt=0;mt<4;mt++) for(int r=0;r<4;r++){
    int o = ro + mt*16 + kq*4 + r;
    float gg = g1[o], bb = b1[o];
    for(int nt=0;nt<2;nt++){
      float x = fmaxf(gg*(acc[mt][nt][r] * BNS) + bb, 0.0f);
      short hi = f2bs(x);
      int n = nt*16 + col;
      vshh[n*VS + o] = hi;
      vshl[n*VS + o] = f2bs(x - bs2f(hi));
    }
  }
  __syncthreads();

  // ---- val = relu(bn2(W_v2 @ v)), split-bf16 ----
  for(int mt=0;mt<4;mt++) for(int nt=0;nt<2;nt++) acc[mt][nt] = vzero;
  for(int ks = 0; ks < 8; ks++){
    bf16x8 bh0 = *(const bf16x8*)&vshh[col*VS + ks*32 + kq*8];
    bf16x8 bh1 = *(const bf16x8*)&vshh[(16+col)*VS + ks*32 + kq*8];
    bf16x8 bl0 = *(const bf16x8*)&vshl[col*VS + ks*32 + kq*8];
    bf16x8 bl1 = *(const bf16x8*)&vshl[(16+col)*VS + ks*32 + kq*8];
    for(int mt = 0; mt < 4; mt++){
      size_t wo = (size_t)(ro + mt*16 + col)*O + ks*32 + kq*8;
      bf16x8 ah = *(const bf16x8*)(v2h + wo);
      bf16x8 al = *(const bf16x8*)(v2l + wo);
      acc[mt][0] = MFMA(al, bh0, MFMA(ah, bl0, MFMA(ah, bh0, acc[mt][0])));
      acc[mt][1] = MFMA(al, bh1, MFMA(ah, bl1, MFMA(ah, bh1, acc[mt][1])));
    }
  }
  for(int mt=0;mt<4;mt++) for(int r=0;r<4;r++){
    int o = ro + mt*16 + kq*4 + r;
    float gg = g2[o], bb = b2[o];
    for(int nt=0;nt<2;nt++){
      float x = fmaxf(gg*(acc[mt][nt][r] * BNS) + bb, 0.0f);
      int n = nt*16 + col;
      valo[((size_t)lq*NS + n)*O + o] = f2bs(x);
    }
  }

  // ---- means over NS (f32) ----
  for(int mt=0;mt<4;mt++) for(int r=0;r<4;r++){
    float sp = 0, sk = 0, spk = 0;
    for(int nt=0;nt<2;nt++){
      sp  += posR[mt][nt][r];
      sk  += keyR[mt][nt][r];
      spk += posR[mt][nt][r] * keyR[mt][nt][r];
    }
    for(int msk=1; msk<16; msk<<=1){
      sp += __shfl_xor(sp, msk); sk += __shfl_xor(sk, msk); spk += __shfl_xor(spk, msk);
    }
    if(col == 0){
      int o = ro + mt*16 + kq*4 + r;
      mPos[lq*O+o] = sp  * 0.03125f;
      mKey[lq*O+o] = sk  * 0.03125f;
      mPK [lq*O+o] = spk * 0.03125f;
    }
  }
}

// ---------------- K3: channel gates, single-bf16 MFMA (16 queries/block) ----------------
__global__ __launch_bounds__(256) void k_gates(
    const float* __restrict__ mPos, const float* __restrict__ mKey,
    const float* __restrict__ mPK, const short* __restrict__ gw,
    float* __restrict__ gates)
{
  int t = threadIdx.x, w = t >> 6, l = t & 63, col = l & 15, kq = l >> 4;
  int lq0 = blockIdx.x * 16;
  const float* A  = (w < 2) ? mPos : ((w == 2) ? mKey : mPK);
  const short* Wg = gw + (size_t)w * O * O;
  f32x4 acc[16];
  const f32x4 vzero = {0.0f,0.0f,0.0f,0.0f};
  for(int i=0;i<16;i++) acc[i] = vzero;
  for(int ks = 0; ks < 8; ks++){
    union { bf16x8 v; short e[8]; } u;
    const float* ap = A + (size_t)(lq0 + col)*O + ks*32 + kq*8;
    for(int j = 0; j < 8; j++) u.e[j] = f2bs(ap[j]);
    for(int nt = 0; nt < 16; nt++){
      bf16x8 bv = *(const bf16x8*)(Wg + (size_t)(nt*16 + col)*O + ks*32 + kq*8);
      acc[nt] = MFMA(u.v, bv, acc[nt]);
    }
  }
  for(int nt=0;nt<16;nt++) for(int r=0;r<4;r++){
    int lqq = lq0 + kq*4 + r;
    int oo = nt*16 + col;
    gates[((size_t)lqq*4 + w)*O + oo] = 1.0f / (1.0f + expf(-acc[nt][r]));
  }
}

// ---------------- K4: per-query attention + new_features (f32) ----------------
__global__ __launch_bounds__(256) void k_attn(
    const short* __restrict__ keyw, const short* __restrict__ valw,
    const float* __restrict__ gxw, const float* __restrict__ posw,
    const float* __restrict__ attw, const float* __restrict__ gates,
    float* __restrict__ nff, float* __restrict__ outNF, int q0)
{
  int lq = blockIdx.x, q = q0 + lq, t = threadIdx.x;
  __shared__ float emL[O * 33];
  __shared__ float attnL[H * NS];
  __shared__ float gxs[NS * 3];
  if(t < 96) gxs[t] = gxw[q*96 + t];
  float vc  = gates[((size_t)lq*4 + 0)*O + t];
  float qc  = gates[((size_t)lq*4 + 1)*O + t];
  float kc  = gates[((size_t)lq*4 + 2)*O + t];
  float qkc = gates[((size_t)lq*4 + 3)*O + t];
  float pw0 = posw[t*3+0], pw1 = posw[t*3+1], pw2 = posw[t*3+2];
  __syncthreads();
  float posr[NS];
  for(int n = 0; n < NS; n++)
    posr[n] = fmaxf(pw0*gxs[n*3] + pw1*gxs[n*3+1] + pw2*gxs[n*3+2], 0.0f);
  for(int n = 0; n < NS; n++){
    float k = bs2f(keyw[((size_t)lq*NS + n)*O + t]);
    emL[t*33 + n] = posr[n]*qc + k*kc + posr[n]*k*qkc;
  }
  __syncthreads();
  if(t < 128){
    int h = t >> 5, n = t & 31;
    float s = 0;
    for(int o = 0; o < O; o++) s += attw[h*O + o] * emL[o*33 + n];
    float mx = s;
    for(int msk=1; msk<32; msk<<=1) mx = fmaxf(mx, __shfl_xor(mx, msk));
    float e = expf(s - mx);
    float sum = e;
    for(int msk=1; msk<32; msk<<=1) sum += __shfl_xor(sum, msk);
    attnL[h*NS + n] = e / sum;
  }
  __syncthreads();
  int h = t >> 6;
  float nf = 0;
  for(int n = 0; n < NS; n++){
    float v = bs2f(valw[((size_t)lq*NS + n)*O + t]);
    nf += (v + posr[n]*vc) * attnL[h*NS + n];
  }
  nff[(size_t)q*O + t] = nf;
  outNF[(size_t)q*O + t] = nf;
}

// ---------------- K5: cls/reg gating MLPs (64 queries/block) ----------------
__global__ __launch_bounds__(256) void k_fgate(
    const float* __restrict__ nff,
    const short* __restrict__ cw1b, const float* __restrict__ cb1,
    const float* __restrict__ cw2, const float* __restrict__ cb2,
    const short* __restrict__ rw1b, const float* __restrict__ rb1,
    const float* __restrict__ rw2, const float* __restrict__ rb2,
    float* __restrict__ outC, float* __restrict__ outR)
{
  int t = threadIdx.x, w = t >> 6, l = t & 63, col = l & 15, kq = l >> 4;
  int q0 = blockIdx.x * 64;
  __shared__ float sC[64], sR[64];
  f32x4 acc[16];
  const f32x4 vzero = {0.0f,0.0f,0.0f,0.0f};
  for(int i=0;i<16;i++) acc[i] = vzero;
  int arow = q0 + w*16 + col;
  for(int ks = 0; ks < 8; ks++){
    union { bf16x8 v; short e[8]; } u;
    const float* ap = nff + (size_t)arow*O + ks*32 + kq*8;
    for(int j = 0; j < 8; j++) u.e[j] = f2bs(ap[j]);
    for(int nt = 0; nt < 16; nt++){
      const short* W1 = (nt < 8) ? cw1b : rw1b;
      int j = (nt & 7)*16 + col;
      bf16x8 bv = *(const bf16x8*)(W1 + (size_t)j*O + ks*32 + kq*8);
      acc[nt] = MFMA(u.v, bv, acc[nt]);
    }
  }
  for(int r = 0; r < 4; r++){
    float pc = 0, pr = 0;
    for(int nt = 0; nt < 8; nt++){
      int j = nt*16 + col;
      pc += fmaxf(acc[nt][r] + cb1[j], 0.0f) * cw2[j];
    }
    for(int nt = 8; nt < 16; nt++){
      int j = (nt - 8)*16 + col;
      pr += fmaxf(acc[nt][r] + rb1[j], 0.0f) * rw2[j];
    }
    for(int msk=1; msk<16; msk<<=1){ pc += __shfl_xor(pc, msk); pr += __shfl_xor(pr, msk); }
    if(col == 0){
      int qq = w*16 + kq*4 + r;
      sC[qq] = 1.0f / (1.0f + expf(-(pc + cb2[0])));
      sR[qq] = 1.0f / (1.0f + expf(-(pr + rb2[0])));
    }
  }
  __syncthreads();
  for(int qq = 0; qq < 64; qq++){
    float nv = nff[(size_t)(q0 + qq)*O + t];
    outC[(size_t)(q0 + qq)*O + t] = nv * sC[qq];
    outR[(size_t)(q0 + qq)*O + t] = nv * sR[qq];
  }
}

extern "C" void kernel_launch(void* const* d_in, const int* in_sizes, int n_in,
                              void* d_out, int out_size, void* d_ws, size_t ws_size,
                              hipStream_t stream)
{
  const float* xyz  = (const float*)d_in[0];
  const float* nxyz = (const float*)d_in[1];
  const float* feat = (const float*)d_in[2];
  const float* posw = (const float*)d_in[3];
  const float* keyw = (const float*)d_in[4];
  const float* v1w  = (const float*)d_in[5];
  const float* bn1g = (const float*)d_in[6];
  const float* bn1b = (const float*)d_in[7];
  const float* v2w  = (const float*)d_in[8];
  const float* bn2g = (const float*)d_in[9];
  const float* bn2b = (const float*)d_in[10];
  const float* attw = (const float*)d_in[11];
  const float* kcw  = (const float*)d_in[12];
  const float* qcw  = (const float*)d_in[13];
  const float* qkcw = (const float*)d_in[14];
  const float* vcw  = (const float*)d_in[15];
  const float* cw1  = (const float*)d_in[16];
  const float* cb1  = (const float*)d_in[17];
  const float* cw2  = (const float*)d_in[18];
  const float* cb2  = (const float*)d_in[19];
  const float* rw1  = (const float*)d_in[20];
  const float* rb1  = (const float*)d_in[21];
  const float* rw2  = (const float*)d_in[22];
  const float* rb2  = (const float*)d_in[23];

  // chunk size from ws_size (deterministic across calls; graph-safe)
  const size_t fixedB = 16000000;        // fT hi/lo + packed weights + idx + gx + nff (+slack)
  const size_t perQ   = 40960;           // keyo+valo (bf16) + means + gates
  int Q = 64;
  for(int cand : {4096, 2048, 1024, 512, 256, 128}){
    if(fixedB + (size_t)cand*perQ <= ws_size){ Q = cand; break; }
  }

  char* p = (char*)d_ws;
  auto alloc = [&](size_t bytes){ char* r = p; p += (bytes + 255) & ~size_t(255); return r; };
  short* fTh   = (short*)alloc((size_t)NTOT*C*2);
  short* fTl   = (short*)alloc((size_t)NTOT*C*2);
  short* keyPh = (short*)alloc((size_t)O*KP*2);
  short* keyPl = (short*)alloc((size_t)O*KP*2);
  short* v1Ph  = (short*)alloc((size_t)O*KP*2);
  short* v1Pl  = (short*)alloc((size_t)O*KP*2);
  short* v2h   = (short*)alloc((size_t)O*O*2);
  short* v2l   = (short*)alloc((size_t)O*O*2);
  short* gw    = (short*)alloc((size_t)4*O*O*2);
  short* cw1b  = (short*)alloc((size_t)(O/2)*O*2);
  short* rw1b  = (short*)alloc((size_t)(O/2)*O*2);
  int*   idxw  = (int*)  alloc((size_t)M*NS*4);
  float* gxw   = (float*)alloc((size_t)M*NS*3*4);
  float* nff   = (float*)alloc((size_t)M*O*4);
  short* keyo  = (short*)alloc((size_t)Q*NS*O*2);
  short* valo  = (short*)alloc((size_t)Q*NS*O*2);
  float* mPos  = (float*)alloc((size_t)Q*O*4);
  float* mKey  = (float*)alloc((size_t)Q*O*4);
  float* mPK   = (float*)alloc((size_t)Q*O*4);
  float* gates = (float*)alloc((size_t)Q*4*O*4);

  float* outNF = (float*)d_out;
  float* outC  = outNF + (size_t)M*O;
  float* outR  = outC  + (size_t)M*O;

  k_transpose<<<256, 256, 0, stream>>>(feat, fTh, fTl);
  k_pack     <<<256, 256, 0, stream>>>(keyw, v1w, v2w, vcw, qcw, kcw, qkcw, cw1, rw1,
                                       keyPh, keyPl, v1Ph, v1Pl, v2h, v2l, gw, cw1b, rw1b);
  k_ballq    <<<M,   64,  0, stream>>>(xyz, nxyz, idxw, gxw);
  for(int q0 = 0; q0 < M; q0 += Q){
    k_conv  <<<Q,    256, 0, stream>>>(fTh, fTl, keyPh, keyPl, v1Ph, v1Pl, v2h, v2l,
                                       posw, bn1g, bn1b, bn2g, bn2b,
                                       idxw, gxw, keyo, valo, mPos, mKey, mPK, q0);
    k_gates <<<Q/16, 256, 0, stream>>>(mPos, mKey, mPK, gw, gates);
    k_attn  <<<Q,    256, 0, stream>>>(keyo, valo, gxw, posw, attw, gates, nff, outNF, q0);
  }
  k_fgate   <<<M/64, 256, 0, stream>>>(nff, cw1b, cb1, cw2, cb2, rw1b, rb1, rw2, rb2, outC, outR);
}

// Round 4
// 491.771 us; speedup vs baseline: 1.1279x; 1.1279x over previous
//
#include <hip/hip_runtime.h>

#define DI __device__ __forceinline__

typedef __attribute__((ext_vector_type(8))) short bf16x8;  // 8 bf16 bit-patterns
typedef __attribute__((ext_vector_type(4))) short s16x4;
typedef __attribute__((ext_vector_type(4))) float f32x4;

DI short f2bs(float x){ unsigned u = __float_as_uint(x);
  return (short)((u + 0x7FFF + ((u >> 16) & 1)) >> 16); }          // RNE f32->bf16
DI float bs2f(short s){ return __uint_as_float(((unsigned)(unsigned short)s) << 16); }
DI f32x4 MFMA(bf16x8 a, bf16x8 b, f32x4 c){
  return __builtin_amdgcn_mfma_f32_16x16x32_bf16(a, b, c, 0, 0, 0);
}

// Problem constants
constexpr int NP   = 8192;
constexpr int NTOT = 16384;     // B*NP (reference flattens batch)
constexpr int M    = 4096;      // B*M_ROIS
constexpr int C    = 128;
constexpr int O    = 256;
constexpr int NS   = 32;
constexpr int H    = 4;
constexpr int KP   = 160;       // padded K: 0..127 feats, 128..130 gx, rest 0
constexpr int GFS  = 168;       // gf LDS row stride (shorts): 336B, 16B-aligned, 2-way banks
constexpr int VS   = 264;       // vbuf LDS row stride (shorts): 528B, 16B-aligned, 2-way banks
constexpr float BNS = 0.99999500003749969f;  // 1/sqrt(1+1e-5)

// coalesced 32x256 bf16 tile copy: LDS (stride VS) -> global (stride O)
DI void copy_rows(short* __restrict__ dst, const short* __restrict__ src, int t){
  int row = t >> 3, s = (t & 7) * 8;
  const short* sp = src + row*VS + s;
  short* dp = dst + (size_t)row*O + s;
  #pragma unroll
  for(int j = 0; j < 4; j++)
    *(bf16x8*)(dp + j*64) = *(const bf16x8*)(sp + j*64);
}

// ---------------- K0a: features (B,C,NP) f32 -> fT hi/lo bf16 [B*NP][C] ----------------
__global__ __launch_bounds__(256) void k_transpose(const float* __restrict__ feat,
                                                   short* __restrict__ fTh,
                                                   short* __restrict__ fTl){
  __shared__ float tile[128][65];
  int blk = blockIdx.x;
  int b  = blk >> 7;
  int n0 = (blk & 127) << 6;
  int t = threadIdx.x;
  int nn = t & 63, c4 = t >> 6;
  const float* src = feat + (size_t)b * C * NP;
  for(int i = 0; i < 32; i++){
    int c = c4 * 32 + i;
    tile[c][nn] = src[(size_t)c * NP + n0 + nn];
  }
  __syncthreads();
  int c2 = t & 127, nb = t >> 7;
  for(int j = 0; j < 32; j++){
    int n = nb + j * 2;
    float v = tile[c2][n];
    short hi = f2bs(v);
    short lo = f2bs(v - bs2f(hi));
    size_t o = ((size_t)(b * NP + n0 + n)) * C + c2;
    fTh[o] = hi; fTl[o] = lo;
  }
}

// ---------------- K0b: pack/split weights ----------------
__global__ __launch_bounds__(256) void k_pack(
    const float* __restrict__ kw, const float* __restrict__ v1w,
    const float* __restrict__ v2w,
    const float* __restrict__ vcw, const float* __restrict__ qcw,
    const float* __restrict__ kcw, const float* __restrict__ qkcw,
    const float* __restrict__ cw1, const float* __restrict__ rw1,
    short* __restrict__ keyPh, short* __restrict__ keyPl,
    short* __restrict__ v1Ph,  short* __restrict__ v1Pl,
    short* __restrict__ v2h,   short* __restrict__ v2l,
    short* __restrict__ gw,            // 4 x O x O bf16 (vc,qc,kc,qkc)
    short* __restrict__ cw1b, short* __restrict__ rw1b)
{
  int i = blockIdx.x * 256 + threadIdx.x;
  if(i < O * KP){
    int o = i / KP, k = i % KP;
    float a = 0.0f, b = 0.0f;
    if(k < 128){ a = kw[o*131 + 3 + k]; b = v1w[o*131 + 3 + k]; }
    else if(k < 131){ a = kw[o*131 + (k - 128)]; b = v1w[o*131 + (k - 128)]; }
    short ah = f2bs(a); keyPh[i] = ah; keyPl[i] = f2bs(a - bs2f(ah));
    short bh = f2bs(b); v1Ph[i]  = bh; v1Pl[i]  = f2bs(b - bs2f(bh));
  }
  if(i < O * O){
    float v = v2w[i];
    short hi = f2bs(v); v2h[i] = hi; v2l[i] = f2bs(v - bs2f(hi));
    gw[0*O*O + i] = f2bs(vcw[i]);
    gw[1*O*O + i] = f2bs(qcw[i]);
    gw[2*O*O + i] = f2bs(kcw[i]);
    gw[3*O*O + i] = f2bs(qkcw[i]);
  }
  if(i < (O/2) * O){
    cw1b[i] = f2bs(cw1[i]);
    rw1b[i] = f2bs(rw1[i]);
  }
}

// ---------------- K1: ball query, 1 wave per query (exact f32) ----------------
__global__ __launch_bounds__(64) void k_ballq(const float* __restrict__ xyz,
                                              const float* __restrict__ nxyz,
                                              int* __restrict__ idxo,
                                              float* __restrict__ gxo){
#pragma clang fp contract(off)
  int m = blockIdx.x;
  int lane = threadIdx.x;
  float qx = nxyz[m*3+0], qy = nxyz[m*3+1], qz = nxyz[m*3+2];
  __shared__ int sel[NS];
  int cnt = 0;
  for(int base = 0; base < NTOT; base += 64){
    int p = base + lane;
    float dx = qx - xyz[p*3+0], dy = qy - xyz[p*3+1], dz = qz - xyz[p*3+2];
    float d2 = dx*dx + dy*dy;     // numpy order: (x^2+y^2)+z^2, no contraction
    d2 = d2 + dz*dz;
    bool pred = d2 < 2.56f;
    unsigned long long bal = __ballot(pred);
    if(pred){
      int pos = cnt + __popcll(bal & ((1ull << lane) - 1ull));
      if(pos < NS) sel[pos] = p;
    }
    cnt += __popcll(bal);
    if(cnt >= NS) break;          // wave-uniform
  }
  __syncthreads();
  if(lane < NS){
    int s = 0;
    if(cnt > 0) s = (lane < cnt) ? sel[lane] : sel[0];  // pad with first; empty -> 0
    idxo[m*NS + lane] = s;
    gxo[(m*NS+lane)*3+0] = xyz[s*3+0] - qx;
    gxo[(m*NS+lane)*3+1] = xyz[s*3+1] - qy;
    gxo[(m*NS+lane)*3+2] = xyz[s*3+2] - qz;
  }
}

// ---------------- K2: fused convs + means (4 blocks/CU, coalesced stores) ----------------
__global__ __launch_bounds__(256, 4) void k_conv(
    const short* __restrict__ fTh, const short* __restrict__ fTl,
    const short* __restrict__ keyPh, const short* __restrict__ keyPl,
    const short* __restrict__ v1Ph, const short* __restrict__ v1Pl,
    const short* __restrict__ v2h, const short* __restrict__ v2l,
    const float* __restrict__ posw,
    const float* __restrict__ g1, const float* __restrict__ b1,
    const float* __restrict__ g2, const float* __restrict__ b2,
    const int* __restrict__ idxw, const float* __restrict__ gxw,
    short* __restrict__ keyo, short* __restrict__ valo,
    float* __restrict__ mPos, float* __restrict__ mKey, float* __restrict__ mPK,
    int q0)
{
  int lq = blockIdx.x, q = q0 + lq, t = threadIdx.x;
  int w = t >> 6, l = t & 63;
  int col = l & 15, kq = l >> 4;
  int ro = w * 64;
  __shared__ __align__(16) short gfh[NS * GFS];   // 10752 B
  __shared__ __align__(16) short gfl[NS * GFS];   // 10752 B
  __shared__ __align__(16) short vbuf[NS * VS];   // 16896 B (key stage -> v -> val stage)
  __shared__ float gxs[NS * 4];                   // 512 B
  __shared__ int  sel[NS];                        // 128 B   total ~39 KB -> 4 blocks/CU
  if(t < NS){
    sel[t] = idxw[q*NS + t];
    gxs[t*4+0] = gxw[(q*NS+t)*3+0];
    gxs[t*4+1] = gxw[(q*NS+t)*3+1];
    gxs[t*4+2] = gxw[(q*NS+t)*3+2];
    gxs[t*4+3] = 0.0f;
  }
  __syncthreads();
  // gather features (hi/lo): wave w -> neighbors 8w..8w+7, lane covers 2 channels (4B)
  for(int i = 0; i < 8; i++){
    int n = w*8 + i;
    int p = sel[n];
    *(unsigned*)&gfh[n*GFS + l*2] = *(const unsigned*)(fTh + (size_t)p * C + l*2);
    *(unsigned*)&gfl[n*GFS + l*2] = *(const unsigned*)(fTl + (size_t)p * C + l*2);
  }
  // gx channels 128..130 + zero pad to 159
  {
    int n = t & 31, kk = (t >> 5) * 4;
    for(int j = 0; j < 4; j++){
      int k = kk + j;
      float v = (k < 3) ? gxs[n*4 + k] : 0.0f;
      short hi = f2bs(v);
      gfh[n*GFS + 128 + k] = hi;
      gfl[n*GFS + 128 + k] = f2bs(v - bs2f(hi));
    }
  }
  __syncthreads();

  // ---- pos = relu(pos_w @ gx), f32 VALU ----
  float posR[4][2][4];
  for(int mt=0;mt<4;mt++) for(int r=0;r<4;r++){
    int o = ro + mt*16 + kq*4 + r;
    float w0 = posw[o*3+0], w1 = posw[o*3+1], w2 = posw[o*3+2];
    for(int nt=0;nt<2;nt++){
      int n = nt*16 + col;
      posR[mt][nt][r] = fmaxf(w0*gxs[n*4+0] + w1*gxs[n*4+1] + w2*gxs[n*4+2], 0.0f);
    }
  }

  f32x4 acc[4][2];
  const f32x4 vzero = {0.0f, 0.0f, 0.0f, 0.0f};

  // ---- key = relu(W_key @ gf), split-bf16 (3-term) ----
  for(int mt=0;mt<4;mt++) for(int nt=0;nt<2;nt++) acc[mt][nt] = vzero;
  for(int ks = 0; ks < 5; ks++){
    bf16x8 bh0 = *(const bf16x8*)&gfh[col*GFS + ks*32 + kq*8];
    bf16x8 bh1 = *(const bf16x8*)&gfh[(16+col)*GFS + ks*32 + kq*8];
    bf16x8 bl0 = *(const bf16x8*)&gfl[col*GFS + ks*32 + kq*8];
    bf16x8 bl1 = *(const bf16x8*)&gfl[(16+col)*GFS + ks*32 + kq*8];
    for(int mt = 0; mt < 4; mt++){
      size_t wo = (size_t)(ro + mt*16 + col)*KP + ks*32 + kq*8;
      bf16x8 ah = *(const bf16x8*)(keyPh + wo);
      bf16x8 al = *(const bf16x8*)(keyPl + wo);
      acc[mt][0] = MFMA(al, bh0, MFMA(ah, bl0, MFMA(ah, bh0, acc[mt][0])));
      acc[mt][1] = MFMA(al, bh1, MFMA(ah, bl1, MFMA(ah, bh1, acc[mt][1])));
    }
  }
  // relu, stage to vbuf[n][o], accumulate mean partials
  float mS[4][4][3];   // [mt][r]{pos,key,poskey}
  for(int mt=0;mt<4;mt++){
    for(int nt=0;nt<2;nt++){
      s16x4 pk;
      for(int r=0;r<4;r++){
        float v = fmaxf(acc[mt][nt][r], 0.0f);
        pk[r] = f2bs(v);
        if(nt == 0){ mS[mt][r][0] = posR[mt][0][r];  mS[mt][r][1] = v;
                     mS[mt][r][2] = posR[mt][0][r]*v; }
        else       { mS[mt][r][0] += posR[mt][1][r]; mS[mt][r][1] += v;
                     mS[mt][r][2] += posR[mt][1][r]*v; }
      }
      int n = nt*16 + col;
      *(s16x4*)&vbuf[n*VS + ro + mt*16 + kq*4] = pk;
    }
  }
  __syncthreads();
  copy_rows(keyo + (size_t)lq*NS*O, vbuf, t);
  // means: reduce across the 16 col lanes
  for(int mt=0;mt<4;mt++) for(int r=0;r<4;r++){
    float sp = mS[mt][r][0], sk = mS[mt][r][1], spk = mS[mt][r][2];
    for(int msk=1; msk<16; msk<<=1){
      sp += __shfl_xor(sp, msk); sk += __shfl_xor(sk, msk); spk += __shfl_xor(spk, msk);
    }
    if(col == 0){
      int o = ro + mt*16 + kq*4 + r;
      mPos[lq*O+o] = sp  * 0.03125f;
      mKey[lq*O+o] = sk  * 0.03125f;
      mPK [lq*O+o] = spk * 0.03125f;
    }
  }

  // ---- v = relu(bn1(W_v1 @ gf)), split-bf16 (3-term) ----
  for(int mt=0;mt<4;mt++) for(int nt=0;nt<2;nt++) acc[mt][nt] = vzero;
  for(int ks = 0; ks < 5; ks++){
    bf16x8 bh0 = *(const bf16x8*)&gfh[col*GFS + ks*32 + kq*8];
    bf16x8 bh1 = *(const bf16x8*)&gfh[(16+col)*GFS + ks*32 + kq*8];
    bf16x8 bl0 = *(const bf16x8*)&gfl[col*GFS + ks*32 + kq*8];
    bf16x8 bl1 = *(const bf16x8*)&gfl[(16+col)*GFS + ks*32 + kq*8];
    for(int mt = 0; mt < 4; mt++){
      size_t wo = (size_t)(ro + mt*16 + col)*KP + ks*32 + kq*8;
      bf16x8 ah = *(const bf16x8*)(v1Ph + wo);
      bf16x8 al = *(const bf16x8*)(v1Pl + wo);
      acc[mt][0] = MFMA(al, bh0, MFMA(ah, bl0, MFMA(ah, bh0, acc[mt][0])));
      acc[mt][1] = MFMA(al, bh1, MFMA(ah, bl1, MFMA(ah, bh1, acc[mt][1])));
    }
  }
  __syncthreads();      // key-stage reads of vbuf complete; safe to overwrite
  for(int mt=0;mt<4;mt++){
    int o0 = ro + mt*16 + kq*4;
    float gg[4], bb[4];
    for(int r=0;r<4;r++){ gg[r] = g1[o0+r]; bb[r] = b1[o0+r]; }
    for(int nt=0;nt<2;nt++){
      s16x4 pk;
      for(int r=0;r<4;r++)
        pk[r] = f2bs(fmaxf(gg[r]*(acc[mt][nt][r] * BNS) + bb[r], 0.0f));
      int n = nt*16 + col;
      *(s16x4*)&vbuf[n*VS + o0] = pk;
    }
  }
  __syncthreads();

  // ---- val = relu(bn2(W_v2 @ v)): act hi-only, weight hi+lo (2-term) ----
  for(int mt=0;mt<4;mt++) for(int nt=0;nt<2;nt++) acc[mt][nt] = vzero;
  for(int ks = 0; ks < 8; ks++){
    bf16x8 bh0 = *(const bf16x8*)&vbuf[col*VS + ks*32 + kq*8];
    bf16x8 bh1 = *(const bf16x8*)&vbuf[(16+col)*VS + ks*32 + kq*8];
    for(int mt = 0; mt < 4; mt++){
      size_t wo = (size_t)(ro + mt*16 + col)*O + ks*32 + kq*8;
      bf16x8 ah = *(const bf16x8*)(v2h + wo);
      bf16x8 al = *(const bf16x8*)(v2l + wo);
      acc[mt][0] = MFMA(al, bh0, MFMA(ah, bh0, acc[mt][0]));
      acc[mt][1] = MFMA(al, bh1, MFMA(ah, bh1, acc[mt][1]));
    }
  }
  s16x4 valS[4][2];
  for(int mt=0;mt<4;mt++){
    int o0 = ro + mt*16 + kq*4;
    float gg[4], bb[4];
    for(int r=0;r<4;r++){ gg[r] = g2[o0+r]; bb[r] = b2[o0+r]; }
    for(int nt=0;nt<2;nt++)
      for(int r=0;r<4;r++)
        valS[mt][nt][r] = f2bs(fmaxf(gg[r]*(acc[mt][nt][r] * BNS) + bb[r], 0.0f));
  }
  __syncthreads();      // v2 reads of vbuf complete
  for(int mt=0;mt<4;mt++) for(int nt=0;nt<2;nt++){
    int n = nt*16 + col;
    *(s16x4*)&vbuf[n*VS + ro + mt*16 + kq*4] = valS[mt][nt];
  }
  __syncthreads();
  copy_rows(valo + (size_t)lq*NS*O, vbuf, t);
}

// ---------------- K3: channel gates, single-bf16 MFMA (16 queries/block) ----------------
__global__ __launch_bounds__(256) void k_gates(
    const float* __restrict__ mPos, const float* __restrict__ mKey,
    const float* __restrict__ mPK, const short* __restrict__ gw,
    float* __restrict__ gates)
{
  int t = threadIdx.x, w = t >> 6, l = t & 63, col = l & 15, kq = l >> 4;
  int lq0 = blockIdx.x * 16;
  const float* A  = (w < 2) ? mPos : ((w == 2) ? mKey : mPK);
  const short* Wg = gw + (size_t)w * O * O;
  f32x4 acc[16];
  const f32x4 vzero = {0.0f,0.0f,0.0f,0.0f};
  for(int i=0;i<16;i++) acc[i] = vzero;
  for(int ks = 0; ks < 8; ks++){
    union { bf16x8 v; short e[8]; } u;
    const float* ap = A + (size_t)(lq0 + col)*O + ks*32 + kq*8;
    for(int j = 0; j < 8; j++) u.e[j] = f2bs(ap[j]);
    for(int nt = 0; nt < 16; nt++){
      bf16x8 bv = *(const bf16x8*)(Wg + (size_t)(nt*16 + col)*O + ks*32 + kq*8);
      acc[nt] = MFMA(u.v, bv, acc[nt]);
    }
  }
  for(int nt=0;nt<16;nt++) for(int r=0;r<4;r++){
    int lqq = lq0 + kq*4 + r;
    int oo = nt*16 + col;
    gates[((size_t)lqq*4 + w)*O + oo] = 1.0f / (1.0f + expf(-acc[nt][r]));
  }
}

// ---------------- K4: per-query attention + new_features (f32) ----------------
__global__ __launch_bounds__(256) void k_attn(
    const short* __restrict__ keyw, const short* __restrict__ valw,
    const float* __restrict__ gxw, const float* __restrict__ posw,
    const float* __restrict__ attw, const float* __restrict__ gates,
    float* __restrict__ nff, float* __restrict__ outNF, int q0)
{
  int lq = blockIdx.x, q = q0 + lq, t = threadIdx.x;
  __shared__ float emL[O * 33];
  __shared__ float attnL[H * NS];
  __shared__ float gxs[NS * 3];
  __shared__ float partial[256];
  if(t < 96) gxs[t] = gxw[q*96 + t];
  float vc  = gates[((size_t)lq*4 + 0)*O + t];
  float qc  = gates[((size_t)lq*4 + 1)*O + t];
  float kc  = gates[((size_t)lq*4 + 2)*O + t];
  float qkc = gates[((size_t)lq*4 + 3)*O + t];
  float pw0 = posw[t*3+0], pw1 = posw[t*3+1], pw2 = posw[t*3+2];
  __syncthreads();
  float posr[NS];
  for(int n = 0; n < NS; n++)
    posr[n] = fmaxf(pw0*gxs[n*3] + pw1*gxs[n*3+1] + pw2*gxs[n*3+2], 0.0f);
  for(int n = 0; n < NS; n++){
    float k = bs2f(keyw[((size_t)lq*NS + n)*O + t]);
    emL[t*33 + n] = posr[n]*qc + k*kc + posr[n]*k*qkc;
  }
  __syncthreads();
  {
    int idx = t & 127, h = idx >> 5, n = idx & 31, half = t >> 7;
    float s = 0;
    const float* aw = attw + h*O + half*128;
    for(int o = 0; o < 128; o++) s += aw[o] * emL[(half*128 + o)*33 + n];
    partial[t] = s;
  }
  __syncthreads();
  if(t < 128){
    int h = t >> 5, n = t & 31;
    float s = partial[t] + partial[t + 128];
    float mx = s;
    for(int msk=1; msk<32; msk<<=1) mx = fmaxf(mx, __shfl_xor(mx, msk));
    float e = expf(s - mx);
    float sum = e;
    for(int msk=1; msk<32; msk<<=1) sum += __shfl_xor(sum, msk);
    attnL[h*NS + n] = e / sum;
  }
  __syncthreads();
  int h = t >> 6;
  float nf = 0;
  for(int n = 0; n < NS; n++){
    float v = bs2f(valw[((size_t)lq*NS + n)*O + t]);
    nf += (v + posr[n]*vc) * attnL[h*NS + n];
  }
  nff[(size_t)q*O + t] = nf;
  outNF[(size_t)q*O + t] = nf;
}

// ---------------- K5: cls/reg gating MLPs (64 queries/block) ----------------
__global__ __launch_bounds__(256) void k_fgate(
    const float* __restrict__ nff,
    const short* __restrict__ cw1b, const float* __restrict__ cb1,
    const float* __restrict__ cw2, const float* __restrict__ cb2,
    const short* __restrict__ rw1b, const float* __restrict__ rb1,
    const float* __restrict__ rw2, const float* __restrict__ rb2,
    float* __restrict__ outC, float* __restrict__ outR)
{
  int t = threadIdx.x, w = t >> 6, l = t & 63, col = l & 15, kq = l >> 4;
  int q0 = blockIdx.x * 64;
  __shared__ float sC[64], sR[64];
  f32x4 acc[16];
  const f32x4 vzero = {0.0f,0.0f,0.0f,0.0f};
  for(int i=0;i<16;i++) acc[i] = vzero;
  int arow = q0 + w*16 + col;
  for(int ks = 0; ks < 8; ks++){
    union { bf16x8 v; short e[8]; } u;
    const float* ap = nff + (size_t)arow*O + ks*32 + kq*8;
    for(int j = 0; j < 8; j++) u.e[j] = f2bs(ap[j]);
    for(int nt = 0; nt < 16; nt++){
      const short* W1 = (nt < 8) ? cw1b : rw1b;
      int j = (nt & 7)*16 + col;
      bf16x8 bv = *(const bf16x8*)(W1 + (size_t)j*O + ks*32 + kq*8);
      acc[nt] = MFMA(u.v, bv, acc[nt]);
    }
  }
  for(int r = 0; r < 4; r++){
    float pc = 0, pr = 0;
    for(int nt = 0; nt < 8; nt++){
      int j = nt*16 + col;
      pc += fmaxf(acc[nt][r] + cb1[j], 0.0f) * cw2[j];
    }
    for(int nt = 8; nt < 16; nt++){
      int j = (nt - 8)*16 + col;
      pr += fmaxf(acc[nt][r] + rb1[j], 0.0f) * rw2[j];
    }
    for(int msk=1; msk<16; msk<<=1){ pc += __shfl_xor(pc, msk); pr += __shfl_xor(pr, msk); }
    if(col == 0){
      int qq = w*16 + kq*4 + r;
      sC[qq] = 1.0f / (1.0f + expf(-(pc + cb2[0])));
      sR[qq] = 1.0f / (1.0f + expf(-(pr + rb2[0])));
    }
  }
  __syncthreads();
  for(int qq = 0; qq < 64; qq++){
    float nv = nff[(size_t)(q0 + qq)*O + t];
    outC[(size_t)(q0 + qq)*O + t] = nv * sC[qq];
    outR[(size_t)(q0 + qq)*O + t] = nv * sR[qq];
  }
}

extern "C" void kernel_launch(void* const* d_in, const int* in_sizes, int n_in,
                              void* d_out, int out_size, void* d_ws, size_t ws_size,
                              hipStream_t stream)
{
  const float* xyz  = (const float*)d_in[0];
  const float* nxyz = (const float*)d_in[1];
  const float* feat = (const float*)d_in[2];
  const float* posw = (const float*)d_in[3];
  const float* keyw = (const float*)d_in[4];
  const float* v1w  = (const float*)d_in[5];
  const float* bn1g = (const float*)d_in[6];
  const float* bn1b = (const float*)d_in[7];
  const float* v2w  = (const float*)d_in[8];
  const float* bn2g = (const float*)d_in[9];
  const float* bn2b = (const float*)d_in[10];
  const float* attw = (const float*)d_in[11];
  const float* kcw  = (const float*)d_in[12];
  const float* qcw  = (const float*)d_in[13];
  const float* qkcw = (const float*)d_in[14];
  const float* vcw  = (const float*)d_in[15];
  const float* cw1  = (const float*)d_in[16];
  const float* cb1  = (const float*)d_in[17];
  const float* cw2  = (const float*)d_in[18];
  const float* cb2  = (const float*)d_in[19];
  const float* rw1  = (const float*)d_in[20];
  const float* rb1  = (const float*)d_in[21];
  const float* rw2  = (const float*)d_in[22];
  const float* rb2  = (const float*)d_in[23];

  // chunk size from ws_size (deterministic across calls; graph-safe)
  const size_t fixedB = 16000000;
  const size_t perQ   = 40960;
  int Q = 64;
  for(int cand : {4096, 2048, 1024, 512, 256, 128}){
    if(fixedB + (size_t)cand*perQ <= ws_size){ Q = cand; break; }
  }

  char* p = (char*)d_ws;
  auto alloc = [&](size_t bytes){ char* r = p; p += (bytes + 255) & ~size_t(255); return r; };
  short* fTh   = (short*)alloc((size_t)NTOT*C*2);
  short* fTl   = (short*)alloc((size_t)NTOT*C*2);
  short* keyPh = (short*)alloc((size_t)O*KP*2);
  short* keyPl = (short*)alloc((size_t)O*KP*2);
  short* v1Ph  = (short*)alloc((size_t)O*KP*2);
  short* v1Pl  = (short*)alloc((size_t)O*KP*2);
  short* v2h   = (short*)alloc((size_t)O*O*2);
  short* v2l   = (short*)alloc((size_t)O*O*2);
  short* gw    = (short*)alloc((size_t)4*O*O*2);
  short* cw1b  = (short*)alloc((size_t)(O/2)*O*2);
  short* rw1b  = (short*)alloc((size_t)(O/2)*O*2);
  int*   idxw  = (int*)  alloc((size_t)M*NS*4);
  float* gxw   = (float*)alloc((size_t)M*NS*3*4);
  float* nff   = (float*)alloc((size_t)M*O*4);
  short* keyo  = (short*)alloc((size_t)Q*NS*O*2);
  short* valo  = (short*)alloc((size_t)Q*NS*O*2);
  float* mPos  = (float*)alloc((size_t)Q*O*4);
  float* mKey  = (float*)alloc((size_t)Q*O*4);
  float* mPK   = (float*)alloc((size_t)Q*O*4);
  float* gates = (float*)alloc((size_t)Q*4*O*4);

  float* outNF = (float*)d_out;
  float* outC  = outNF + (size_t)M*O;
  float* outR  = outC  + (size_t)M*O;

  k_transpose<<<256, 256, 0, stream>>>(feat, fTh, fTl);
  k_pack     <<<256, 256, 0, stream>>>(keyw, v1w, v2w, vcw, qcw, kcw, qkcw, cw1, rw1,
                                       keyPh, keyPl, v1Ph, v1Pl, v2h, v2l, gw, cw1b, rw1b);
  k_ballq    <<<M,   64,  0, stream>>>(xyz, nxyz, idxw, gxw);
  for(int q0 = 0; q0 < M; q0 += Q){
    k_conv  <<<Q,    256, 0, stream>>>(fTh, fTl, keyPh, keyPl, v1Ph, v1Pl, v2h, v2l,
                                       posw, bn1g, bn1b, bn2g, bn2b,
                                       idxw, gxw, keyo, valo, mPos, mKey, mPK, q0);
    k_gates <<<Q/16, 256, 0, stream>>>(mPos, mKey, mPK, gw, gates);
    k_attn  <<<Q,    256, 0, stream>>>(keyo, valo, gxw, posw, attw, gates, nff, outNF, q0);
  }
  k_fgate   <<<M/64, 256, 0, stream>>>(nff, cw1b, cb1, cw2, cb2, rw1b, rb1, rw2, rb2, outC, outR);
}

// Round 5
// 408.740 us; speedup vs baseline: 1.3570x; 1.2031x over previous
//
#include <hip/hip_runtime.h>

#define DI __device__ __forceinline__

typedef __attribute__((ext_vector_type(8))) short bf16x8;  // 8 bf16 bit-patterns
typedef __attribute__((ext_vector_type(4))) short s16x4;
typedef __attribute__((ext_vector_type(4))) float f32x4;

DI short f2bs(float x){ unsigned u = __float_as_uint(x);
  return (short)((u + 0x7FFF + ((u >> 16) & 1)) >> 16); }          // RNE f32->bf16
DI float bs2f(short s){ return __uint_as_float(((unsigned)(unsigned short)s) << 16); }
DI f32x4 MFMA(bf16x8 a, bf16x8 b, f32x4 c){
  return __builtin_amdgcn_mfma_f32_16x16x32_bf16(a, b, c, 0, 0, 0);
}

// Problem constants
constexpr int NP   = 8192;
constexpr int NTOT = 16384;     // B*NP (reference flattens batch)
constexpr int M    = 4096;      // B*M_ROIS
constexpr int C    = 128;
constexpr int O    = 256;
constexpr int NS   = 32;
constexpr int H    = 4;
constexpr int KP   = 160;       // padded K: 0..127 feats, 128..130 gx, rest 0
constexpr int GFS  = 168;       // gf LDS row stride (shorts): 336B, 16B-aligned, 2-way banks
constexpr int VS   = 264;       // vbuf LDS row stride (shorts): 528B, 16B-aligned, 2-way banks
constexpr float BNS = 0.99999500003749969f;  // 1/sqrt(1+1e-5)

// coalesced 32x256 bf16 tile copy: LDS (stride VS) -> global (stride O)
DI void copy_rows(short* __restrict__ dst, const short* __restrict__ src, int t){
  int row = t >> 3, s = (t & 7) * 8;
  const short* sp = src + row*VS + s;
  short* dp = dst + (size_t)row*O + s;
  #pragma unroll
  for(int j = 0; j < 4; j++)
    *(bf16x8*)(dp + j*64) = *(const bf16x8*)(sp + j*64);
}

// ---------------- K0a: features (B,C,NP) f32 -> fT bf16 [B*NP][C] ----------------
__global__ __launch_bounds__(256) void k_transpose(const float* __restrict__ feat,
                                                   short* __restrict__ fT){
  __shared__ float tile[128][65];
  int blk = blockIdx.x;
  int b  = blk >> 7;
  int n0 = (blk & 127) << 6;
  int t = threadIdx.x;
  int nn = t & 63, c4 = t >> 6;
  const float* src = feat + (size_t)b * C * NP;
  for(int i = 0; i < 32; i++){
    int c = c4 * 32 + i;
    tile[c][nn] = src[(size_t)c * NP + n0 + nn];
  }
  __syncthreads();
  int c2 = t & 127, nb = t >> 7;
  for(int j = 0; j < 32; j++){
    int n = nb + j * 2;
    fT[((size_t)(b * NP + n0 + n)) * C + c2] = f2bs(tile[c2][n]);
  }
}

// ---------------- K0b: pack weights (bf16) ----------------
__global__ __launch_bounds__(256) void k_pack(
    const float* __restrict__ kw, const float* __restrict__ v1w,
    const float* __restrict__ v2w,
    const float* __restrict__ vcw, const float* __restrict__ qcw,
    const float* __restrict__ kcw, const float* __restrict__ qkcw,
    const float* __restrict__ cw1, const float* __restrict__ rw1,
    short* __restrict__ keyP, short* __restrict__ v1P,
    short* __restrict__ v2b,
    short* __restrict__ gw,            // 4 x O x O bf16 (vc,qc,kc,qkc)
    short* __restrict__ cw1b, short* __restrict__ rw1b)
{
  int i = blockIdx.x * 256 + threadIdx.x;
  if(i < O * KP){
    int o = i / KP, k = i % KP;
    float a = 0.0f, b = 0.0f;
    if(k < 128){ a = kw[o*131 + 3 + k]; b = v1w[o*131 + 3 + k]; }
    else if(k < 131){ a = kw[o*131 + (k - 128)]; b = v1w[o*131 + (k - 128)]; }
    keyP[i] = f2bs(a);
    v1P[i]  = f2bs(b);
  }
  if(i < O * O){
    v2b[i] = f2bs(v2w[i]);
    gw[0*O*O + i] = f2bs(vcw[i]);
    gw[1*O*O + i] = f2bs(qcw[i]);
    gw[2*O*O + i] = f2bs(kcw[i]);
    gw[3*O*O + i] = f2bs(qkcw[i]);
  }
  if(i < (O/2) * O){
    cw1b[i] = f2bs(cw1[i]);
    rw1b[i] = f2bs(rw1[i]);
  }
}

// ---------------- K1: ball query, 1 wave per query (exact f32) ----------------
__global__ __launch_bounds__(64) void k_ballq(const float* __restrict__ xyz,
                                              const float* __restrict__ nxyz,
                                              int* __restrict__ idxo,
                                              float* __restrict__ gxo){
#pragma clang fp contract(off)
  int m = blockIdx.x;
  int lane = threadIdx.x;
  float qx = nxyz[m*3+0], qy = nxyz[m*3+1], qz = nxyz[m*3+2];
  __shared__ int sel[NS];
  int cnt = 0;
  for(int base = 0; base < NTOT; base += 64){
    int p = base + lane;
    float dx = qx - xyz[p*3+0], dy = qy - xyz[p*3+1], dz = qz - xyz[p*3+2];
    float d2 = dx*dx + dy*dy;     // numpy order: (x^2+y^2)+z^2, no contraction
    d2 = d2 + dz*dz;
    bool pred = d2 < 2.56f;
    unsigned long long bal = __ballot(pred);
    if(pred){
      int pos = cnt + __popcll(bal & ((1ull << lane) - 1ull));
      if(pos < NS) sel[pos] = p;
    }
    cnt += __popcll(bal);
    if(cnt >= NS) break;          // wave-uniform
  }
  __syncthreads();
  if(lane < NS){
    int s = 0;
    if(cnt > 0) s = (lane < cnt) ? sel[lane] : sel[0];  // pad with first; empty -> 0
    idxo[m*NS + lane] = s;
    gxo[(m*NS+lane)*3+0] = xyz[s*3+0] - qx;
    gxo[(m*NS+lane)*3+1] = xyz[s*3+1] - qy;
    gxo[(m*NS+lane)*3+2] = xyz[s*3+2] - qz;
  }
}

// ---------------- K2: fused convs + means (pure bf16 MFMA, 5 blocks/CU) ----------------
__global__ __launch_bounds__(256, 5) void k_conv(
    const short* __restrict__ fT,
    const short* __restrict__ keyP, const short* __restrict__ v1P,
    const short* __restrict__ v2b,
    const float* __restrict__ posw,
    const float* __restrict__ g1, const float* __restrict__ b1,
    const float* __restrict__ g2, const float* __restrict__ b2,
    const int* __restrict__ idxw, const float* __restrict__ gxw,
    short* __restrict__ keyo, short* __restrict__ valo,
    float* __restrict__ mPos, float* __restrict__ mKey, float* __restrict__ mPK,
    int q0)
{
  int lq = blockIdx.x, q = q0 + lq, t = threadIdx.x;
  int w = t >> 6, l = t & 63;
  int col = l & 15, kq = l >> 4;
  int ro = w * 64;
  __shared__ __align__(16) short gf[NS * GFS];    // 10752 B
  __shared__ __align__(16) short vbuf[NS * VS];   // 16896 B (key -> v -> val staging)
  __shared__ float gxs[NS * 4];                   // 512 B
  __shared__ int  sel[NS];                        // 128 B   total ~27.6 KB -> 5 blocks/CU
  if(t < NS){
    sel[t] = idxw[q*NS + t];
    gxs[t*4+0] = gxw[(q*NS+t)*3+0];
    gxs[t*4+1] = gxw[(q*NS+t)*3+1];
    gxs[t*4+2] = gxw[(q*NS+t)*3+2];
    gxs[t*4+3] = 0.0f;
  }
  __syncthreads();
  // gather features: wave w -> neighbors 8w..8w+7, lane covers 2 channels (4B)
  for(int i = 0; i < 8; i++){
    int n = w*8 + i;
    int p = sel[n];
    *(unsigned*)&gf[n*GFS + l*2] = *(const unsigned*)(fT + (size_t)p * C + l*2);
  }
  // gx channels 128..130 + zero pad to 159
  {
    int n = t & 31, kk = (t >> 5) * 4;
    for(int j = 0; j < 4; j++){
      int k = kk + j;
      float v = (k < 3) ? gxs[n*4 + k] : 0.0f;
      gf[n*GFS + 128 + k] = f2bs(v);
    }
  }
  __syncthreads();

  // ---- pos = relu(pos_w @ gx), f32 VALU ----
  float posR[4][2][4];
  for(int mt=0;mt<4;mt++) for(int r=0;r<4;r++){
    int o = ro + mt*16 + kq*4 + r;
    float w0 = posw[o*3+0], w1 = posw[o*3+1], w2 = posw[o*3+2];
    for(int nt=0;nt<2;nt++){
      int n = nt*16 + col;
      posR[mt][nt][r] = fmaxf(w0*gxs[n*4+0] + w1*gxs[n*4+1] + w2*gxs[n*4+2], 0.0f);
    }
  }

  f32x4 acc[4][2];
  const f32x4 vzero = {0.0f, 0.0f, 0.0f, 0.0f};

  // ---- key = relu(W_key @ gf) ----
  for(int mt=0;mt<4;mt++) for(int nt=0;nt<2;nt++) acc[mt][nt] = vzero;
  for(int ks = 0; ks < 5; ks++){
    bf16x8 b0 = *(const bf16x8*)&gf[col*GFS + ks*32 + kq*8];
    bf16x8 b1v = *(const bf16x8*)&gf[(16+col)*GFS + ks*32 + kq*8];
    for(int mt = 0; mt < 4; mt++){
      bf16x8 a = *(const bf16x8*)(keyP + (size_t)(ro + mt*16 + col)*KP + ks*32 + kq*8);
      acc[mt][0] = MFMA(a, b0, acc[mt][0]);
      acc[mt][1] = MFMA(a, b1v, acc[mt][1]);
    }
  }
  // relu, stage to vbuf[n][o], accumulate mean partials
  float mS[4][4][3];   // [mt][r]{pos,key,poskey}
  for(int mt=0;mt<4;mt++){
    for(int nt=0;nt<2;nt++){
      s16x4 pk;
      for(int r=0;r<4;r++){
        float v = fmaxf(acc[mt][nt][r], 0.0f);
        pk[r] = f2bs(v);
        if(nt == 0){ mS[mt][r][0] = posR[mt][0][r];  mS[mt][r][1] = v;
                     mS[mt][r][2] = posR[mt][0][r]*v; }
        else       { mS[mt][r][0] += posR[mt][1][r]; mS[mt][r][1] += v;
                     mS[mt][r][2] += posR[mt][1][r]*v; }
      }
      int n = nt*16 + col;
      *(s16x4*)&vbuf[n*VS + ro + mt*16 + kq*4] = pk;
    }
  }
  __syncthreads();
  copy_rows(keyo + (size_t)lq*NS*O, vbuf, t);
  // means: reduce across the 16 col lanes
  for(int mt=0;mt<4;mt++) for(int r=0;r<4;r++){
    float sp = mS[mt][r][0], sk = mS[mt][r][1], spk = mS[mt][r][2];
    for(int msk=1; msk<16; msk<<=1){
      sp += __shfl_xor(sp, msk); sk += __shfl_xor(sk, msk); spk += __shfl_xor(spk, msk);
    }
    if(col == 0){
      int o = ro + mt*16 + kq*4 + r;
      mPos[lq*O+o] = sp  * 0.03125f;
      mKey[lq*O+o] = sk  * 0.03125f;
      mPK [lq*O+o] = spk * 0.03125f;
    }
  }

  // ---- v = relu(bn1(W_v1 @ gf)) ----
  for(int mt=0;mt<4;mt++) for(int nt=0;nt<2;nt++) acc[mt][nt] = vzero;
  for(int ks = 0; ks < 5; ks++){
    bf16x8 b0 = *(const bf16x8*)&gf[col*GFS + ks*32 + kq*8];
    bf16x8 b1v = *(const bf16x8*)&gf[(16+col)*GFS + ks*32 + kq*8];
    for(int mt = 0; mt < 4; mt++){
      bf16x8 a = *(const bf16x8*)(v1P + (size_t)(ro + mt*16 + col)*KP + ks*32 + kq*8);
      acc[mt][0] = MFMA(a, b0, acc[mt][0]);
      acc[mt][1] = MFMA(a, b1v, acc[mt][1]);
    }
  }
  __syncthreads();      // key-stage reads of vbuf complete; safe to overwrite
  for(int mt=0;mt<4;mt++){
    int o0 = ro + mt*16 + kq*4;
    float gg[4], bb[4];
    for(int r=0;r<4;r++){ gg[r] = g1[o0+r]; bb[r] = b1[o0+r]; }
    for(int nt=0;nt<2;nt++){
      s16x4 pk;
      for(int r=0;r<4;r++)
        pk[r] = f2bs(fmaxf(gg[r]*(acc[mt][nt][r] * BNS) + bb[r], 0.0f));
      int n = nt*16 + col;
      *(s16x4*)&vbuf[n*VS + o0] = pk;
    }
  }
  __syncthreads();

  // ---- val = relu(bn2(W_v2 @ v)) ----
  for(int mt=0;mt<4;mt++) for(int nt=0;nt<2;nt++) acc[mt][nt] = vzero;
  for(int ks = 0; ks < 8; ks++){
    bf16x8 b0 = *(const bf16x8*)&vbuf[col*VS + ks*32 + kq*8];
    bf16x8 b1v = *(const bf16x8*)&vbuf[(16+col)*VS + ks*32 + kq*8];
    for(int mt = 0; mt < 4; mt++){
      bf16x8 a = *(const bf16x8*)(v2b + (size_t)(ro + mt*16 + col)*O + ks*32 + kq*8);
      acc[mt][0] = MFMA(a, b0, acc[mt][0]);
      acc[mt][1] = MFMA(a, b1v, acc[mt][1]);
    }
  }
  s16x4 valS[4][2];
  for(int mt=0;mt<4;mt++){
    int o0 = ro + mt*16 + kq*4;
    float gg[4], bb[4];
    for(int r=0;r<4;r++){ gg[r] = g2[o0+r]; bb[r] = b2[o0+r]; }
    for(int nt=0;nt<2;nt++)
      for(int r=0;r<4;r++)
        valS[mt][nt][r] = f2bs(fmaxf(gg[r]*(acc[mt][nt][r] * BNS) + bb[r], 0.0f));
  }
  __syncthreads();      // v2 reads of vbuf complete
  for(int mt=0;mt<4;mt++) for(int nt=0;nt<2;nt++){
    int n = nt*16 + col;
    *(s16x4*)&vbuf[n*VS + ro + mt*16 + kq*4] = valS[mt][nt];
  }
  __syncthreads();
  copy_rows(valo + (size_t)lq*NS*O, vbuf, t);
}

// ---------------- K3: channel gates, batched MFMA (16 queries/block) ----------------
__global__ __launch_bounds__(256) void k_gates(
    const float* __restrict__ mPos, const float* __restrict__ mKey,
    const float* __restrict__ mPK, const short* __restrict__ gw,
    float* __restrict__ gates)
{
  int t = threadIdx.x, w = t >> 6, l = t & 63, col = l & 15, kq = l >> 4;
  int lq0 = blockIdx.x * 16;
  const float* A  = (w < 2) ? mPos : ((w == 2) ? mKey : mPK);
  const short* Wg = gw + (size_t)w * O * O;
  f32x4 acc[16];
  const f32x4 vzero = {0.0f,0.0f,0.0f,0.0f};
  for(int i=0;i<16;i++) acc[i] = vzero;
  for(int ks = 0; ks < 8; ks++){
    union { bf16x8 v; short e[8]; } u;
    const float* ap = A + (size_t)(lq0 + col)*O + ks*32 + kq*8;
    for(int j = 0; j < 8; j++) u.e[j] = f2bs(ap[j]);
    for(int nt = 0; nt < 16; nt++){
      bf16x8 bv = *(const bf16x8*)(Wg + (size_t)(nt*16 + col)*O + ks*32 + kq*8);
      acc[nt] = MFMA(u.v, bv, acc[nt]);
    }
  }
  for(int nt=0;nt<16;nt++) for(int r=0;r<4;r++){
    int lqq = lq0 + kq*4 + r;
    int oo = nt*16 + col;
    gates[((size_t)lqq*4 + w)*O + oo] = 1.0f / (1.0f + expf(-acc[nt][r]));
  }
}

// ---------------- K4: per-query attention + new_features (f32) ----------------
__global__ __launch_bounds__(256) void k_attn(
    const short* __restrict__ keyw, const short* __restrict__ valw,
    const float* __restrict__ gxw, const float* __restrict__ posw,
    const float* __restrict__ attw, const float* __restrict__ gates,
    float* __restrict__ outNF, int q0)
{
  int lq = blockIdx.x, q = q0 + lq, t = threadIdx.x;
  __shared__ float emL[O * 33];
  __shared__ float attnL[H * NS];
  __shared__ float gxs[NS * 3];
  __shared__ float partial[256];
  if(t < 96) gxs[t] = gxw[q*96 + t];
  float vc  = gates[((size_t)lq*4 + 0)*O + t];
  float qc  = gates[((size_t)lq*4 + 1)*O + t];
  float kc  = gates[((size_t)lq*4 + 2)*O + t];
  float qkc = gates[((size_t)lq*4 + 3)*O + t];
  float pw0 = posw[t*3+0], pw1 = posw[t*3+1], pw2 = posw[t*3+2];
  __syncthreads();
  float posr[NS];
  for(int n = 0; n < NS; n++)
    posr[n] = fmaxf(pw0*gxs[n*3] + pw1*gxs[n*3+1] + pw2*gxs[n*3+2], 0.0f);
  for(int n = 0; n < NS; n++){
    float k = bs2f(keyw[((size_t)lq*NS + n)*O + t]);
    emL[t*33 + n] = posr[n]*qc + k*kc + posr[n]*k*qkc;
  }
  __syncthreads();
  {
    int idx = t & 127, h = idx >> 5, n = idx & 31, half = t >> 7;
    float s = 0;
    const float* aw = attw + h*O + half*128;
    for(int o = 0; o < 128; o++) s += aw[o] * emL[(half*128 + o)*33 + n];
    partial[t] = s;
  }
  __syncthreads();
  if(t < 128){
    int h = t >> 5, n = t & 31;
    float s = partial[t] + partial[t + 128];
    float mx = s;
    for(int msk=1; msk<32; msk<<=1) mx = fmaxf(mx, __shfl_xor(mx, msk));
    float e = expf(s - mx);
    float sum = e;
    for(int msk=1; msk<32; msk<<=1) sum += __shfl_xor(sum, msk);
    attnL[h*NS + n] = e / sum;
  }
  __syncthreads();
  int h = t >> 6;
  float nf = 0;
  for(int n = 0; n < NS; n++){
    float v = bs2f(valw[((size_t)lq*NS + n)*O + t]);
    nf += (v + posr[n]*vc) * attnL[h*NS + n];
  }
  outNF[(size_t)q*O + t] = nf;
}

// ---------------- K5: cls/reg gating MLPs (64 queries/block) ----------------
__global__ __launch_bounds__(256) void k_fgate(
    const float* __restrict__ nf,            // = outNF (written by k_attn this launch)
    const short* __restrict__ cw1b, const float* __restrict__ cb1,
    const float* __restrict__ cw2, const float* __restrict__ cb2,
    const short* __restrict__ rw1b, const float* __restrict__ rb1,
    const float* __restrict__ rw2, const float* __restrict__ rb2,
    float* __restrict__ outC, float* __restrict__ outR)
{
  int t = threadIdx.x, w = t >> 6, l = t & 63, col = l & 15, kq = l >> 4;
  int q0 = blockIdx.x * 64;
  __shared__ float sC[64], sR[64];
  f32x4 acc[16];
  const f32x4 vzero = {0.0f,0.0f,0.0f,0.0f};
  for(int i=0;i<16;i++) acc[i] = vzero;
  int arow = q0 + w*16 + col;
  for(int ks = 0; ks < 8; ks++){
    union { bf16x8 v; short e[8]; } u;
    const float* ap = nf + (size_t)arow*O + ks*32 + kq*8;
    for(int j = 0; j < 8; j++) u.e[j] = f2bs(ap[j]);
    for(int nt = 0; nt < 16; nt++){
      const short* W1 = (nt < 8) ? cw1b : rw1b;
      int j = (nt & 7)*16 + col;
      bf16x8 bv = *(const bf16x8*)(W1 + (size_t)j*O + ks*32 + kq*8);
      acc[nt] = MFMA(u.v, bv, acc[nt]);
    }
  }
  for(int r = 0; r < 4; r++){
    float pc = 0, pr = 0;
    for(int nt = 0; nt < 8; nt++){
      int j = nt*16 + col;
      pc += fmaxf(acc[nt][r] + cb1[j], 0.0f) * cw2[j];
    }
    for(int nt = 8; nt < 16; nt++){
      int j = (nt - 8)*16 + col;
      pr += fmaxf(acc[nt][r] + rb1[j], 0.0f) * rw2[j];
    }
    for(int msk=1; msk<16; msk<<=1){ pc += __shfl_xor(pc, msk); pr += __shfl_xor(pr, msk); }
    if(col == 0){
      int qq = w*16 + kq*4 + r;
      sC[qq] = 1.0f / (1.0f + expf(-(pc + cb2[0])));
      sR[qq] = 1.0f / (1.0f + expf(-(pr + rb2[0])));
    }
  }
  __syncthreads();
  for(int qq = 0; qq < 64; qq++){
    float nv = nf[(size_t)(q0 + qq)*O + t];
    outC[(size_t)(q0 + qq)*O + t] = nv * sC[qq];
    outR[(size_t)(q0 + qq)*O + t] = nv * sR[qq];
  }
}

extern "C" void kernel_launch(void* const* d_in, const int* in_sizes, int n_in,
                              void* d_out, int out_size, void* d_ws, size_t ws_size,
                              hipStream_t stream)
{
  const float* xyz  = (const float*)d_in[0];
  const float* nxyz = (const float*)d_in[1];
  const float* feat = (const float*)d_in[2];
  const float* posw = (const float*)d_in[3];
  const float* keyw = (const float*)d_in[4];
  const float* v1w  = (const float*)d_in[5];
  const float* bn1g = (const float*)d_in[6];
  const float* bn1b = (const float*)d_in[7];
  const float* v2w  = (const float*)d_in[8];
  const float* bn2g = (const float*)d_in[9];
  const float* bn2b = (const float*)d_in[10];
  const float* attw = (const float*)d_in[11];
  const float* kcw  = (const float*)d_in[12];
  const float* qcw  = (const float*)d_in[13];
  const float* qkcw = (const float*)d_in[14];
  const float* vcw  = (const float*)d_in[15];
  const float* cw1  = (const float*)d_in[16];
  const float* cb1  = (const float*)d_in[17];
  const float* cw2  = (const float*)d_in[18];
  const float* cb2  = (const float*)d_in[19];
  const float* rw1  = (const float*)d_in[20];
  const float* rb1  = (const float*)d_in[21];
  const float* rw2  = (const float*)d_in[22];
  const float* rb2  = (const float*)d_in[23];

  // chunk size from ws_size (deterministic across calls; graph-safe)
  const size_t fixedB = 12000000;
  const size_t perQ   = 40960;
  int Q = 64;
  for(int cand : {4096, 2048, 1024, 512, 256, 128}){
    if(fixedB + (size_t)cand*perQ <= ws_size){ Q = cand; break; }
  }

  char* p = (char*)d_ws;
  auto alloc = [&](size_t bytes){ char* r = p; p += (bytes + 255) & ~size_t(255); return r; };
  short* fT    = (short*)alloc((size_t)NTOT*C*2);
  short* keyP  = (short*)alloc((size_t)O*KP*2);
  short* v1P   = (short*)alloc((size_t)O*KP*2);
  short* v2b   = (short*)alloc((size_t)O*O*2);
  short* gw    = (short*)alloc((size_t)4*O*O*2);
  short* cw1b  = (short*)alloc((size_t)(O/2)*O*2);
  short* rw1b  = (short*)alloc((size_t)(O/2)*O*2);
  int*   idxw  = (int*)  alloc((size_t)M*NS*4);
  float* gxw   = (float*)alloc((size_t)M*NS*3*4);
  short* keyo  = (short*)alloc((size_t)Q*NS*O*2);
  short* valo  = (short*)alloc((size_t)Q*NS*O*2);
  float* mPos  = (float*)alloc((size_t)Q*O*4);
  float* mKey  = (float*)alloc((size_t)Q*O*4);
  float* mPK   = (float*)alloc((size_t)Q*O*4);
  float* gates = (float*)alloc((size_t)Q*4*O*4);

  float* outNF = (float*)d_out;
  float* outC  = outNF + (size_t)M*O;
  float* outR  = outC  + (size_t)M*O;

  k_transpose<<<256, 256, 0, stream>>>(feat, fT);
  k_pack     <<<256, 256, 0, stream>>>(keyw, v1w, v2w, vcw, qcw, kcw, qkcw, cw1, rw1,
                                       keyP, v1P, v2b, gw, cw1b, rw1b);
  k_ballq    <<<M,   64,  0, stream>>>(xyz, nxyz, idxw, gxw);
  for(int q0 = 0; q0 < M; q0 += Q){
    k_conv  <<<Q,    256, 0, stream>>>(fT, keyP, v1P, v2b,
                                       posw, bn1g, bn1b, bn2g, bn2b,
                                       idxw, gxw, keyo, valo, mPos, mKey, mPK, q0);
    k_gates <<<Q/16, 256, 0, stream>>>(mPos, mKey, mPK, gw, gates);
    k_attn  <<<Q,    256, 0, stream>>>(keyo, valo, gxw, posw, attw, gates, outNF, q0);
  }
  k_fgate   <<<M/64, 256, 0, stream>>>(outNF, cw1b, cb1, cw2, cb2, rw1b, rb1, rw2, rb2, outC, outR);
}